// Round 1
// baseline (245.701 us; speedup 1.0000x reference)
//
#include <hip/hip_runtime.h>

// ScopeWiseSum: out[s,d,b,j] = log(sum_k exp(x[s,d,b,k]-max_k x) * acc[s,d,k,j]/colsum_j) + max_k x
// (the max_b term of the reference's logmatmul cancels analytically against the
//  log_softmax normalization; weight side needs NO log/exp, only a column-sum divide)
//
// S=128, D=8, B=1024, K=32, J=32.  1024 (s,d) pairs, each a [1024x32]@[32x32] job.
// Memory-bound: 272 MB traffic -> ~43 us floor at 6.3 TB/s.

#define KDIM 32
#define JDIM 32
#define ROWS 256      // rows per block
#define THREADS 256
#define XPAD 33       // LDS row stride (+1 float) -> phase-2 row reads rotate banks

__global__ __launch_bounds__(THREADS, 4) void sws_kernel(
    const float* __restrict__ x,
    const float* __restrict__ acc,
    float* __restrict__ out)
{
    __shared__ float w_lds[KDIM * JDIM];   // acc tile, then column-normalized weights
    __shared__ float inv_lds[JDIM];        // 1/colsum
    __shared__ float x_lds[ROWS * XPAD];   // padded x tile

    const int t   = threadIdx.x;
    const int blk = blockIdx.x;
    const int sd  = blk >> 2;              // 4 row-tiles per (s,d)

    const float4* x4     = (const float4*)(x + (size_t)blk * ROWS * KDIM);
    const float*  a_base = acc + (size_t)sd * (KDIM * JDIM);

    // ---- issue x global loads early (coalesced: lane i -> consecutive float4) ----
    float4 xv4[8];
#pragma unroll
    for (int i = 0; i < 8; ++i) xv4[i] = x4[t + i * THREADS];

    // ---- phase 0: load acc tile, column-normalize ----
    {
        float av[4];
#pragma unroll
        for (int i = 0; i < 4; ++i) av[i] = a_base[t + i * THREADS];
#pragma unroll
        for (int i = 0; i < 4; ++i) w_lds[t + i * THREADS] = av[i];
    }
    __syncthreads();
    if (t < JDIM) {
        // lane j sums column j; addr k*32+j -> bank j, conflict-free
        float s = 0.f;
#pragma unroll
        for (int k = 0; k < KDIM; ++k) s += w_lds[k * JDIM + t];
        inv_lds[t] = 1.0f / s;
    }
    __syncthreads();
#pragma unroll
    for (int i = 0; i < 4; ++i) {
        int idx = t + i * THREADS;
        w_lds[idx] *= inv_lds[idx & (JDIM - 1)];
    }
    // (the phase-1 barrier below also publishes the normalized weights)

    // ---- phase 1: stage x tile to LDS with +1 padding ----
#pragma unroll
    for (int i = 0; i < 8; ++i) {
        int f   = t + i * THREADS;   // flat float4 index in tile
        int row = f >> 3;            // 8 float4 per row
        int c   = (f & 7) * 4;
        float* p = &x_lds[row * XPAD + c];
        p[0] = xv4[i].x; p[1] = xv4[i].y; p[2] = xv4[i].z; p[3] = xv4[i].w;
    }
    __syncthreads();

    // ---- phase 2: thread t owns row t ----
    float e[KDIM];
#pragma unroll
    for (int k = 0; k < KDIM; ++k) e[k] = x_lds[t * XPAD + k];  // bank (t+k)%32: free

    float m = e[0];
#pragma unroll
    for (int k = 1; k < KDIM; ++k) m = fmaxf(m, e[k]);
#pragma unroll
    for (int k = 0; k < KDIM; ++k) e[k] = __expf(e[k] - m);

    float accv[JDIM];
#pragma unroll
    for (int j = 0; j < JDIM; ++j) accv[j] = 0.f;

#pragma unroll
    for (int k = 0; k < KDIM; ++k) {
        float ek = e[k];
        const float4* wr = (const float4*)(w_lds + k * JDIM);  // wave-uniform addr: broadcast
#pragma unroll
        for (int j4 = 0; j4 < 8; ++j4) {
            float4 w = wr[j4];
            accv[4 * j4 + 0] = fmaf(ek, w.x, accv[4 * j4 + 0]);
            accv[4 * j4 + 1] = fmaf(ek, w.y, accv[4 * j4 + 1]);
            accv[4 * j4 + 2] = fmaf(ek, w.z, accv[4 * j4 + 2]);
            accv[4 * j4 + 3] = fmaf(ek, w.w, accv[4 * j4 + 3]);
        }
    }

    // ---- epilogue: log + add row max, direct dwordx4 stores (each 128B line fully
    //      written by one lane across 8 stores; L2 write-combines) ----
    float4* o4 = (float4*)(out + (size_t)blk * ROWS * KDIM + (size_t)t * KDIM);
#pragma unroll
    for (int j4 = 0; j4 < 8; ++j4) {
        float4 o;
        o.x = __logf(accv[4 * j4 + 0]) + m;
        o.y = __logf(accv[4 * j4 + 1]) + m;
        o.z = __logf(accv[4 * j4 + 2]) + m;
        o.w = __logf(accv[4 * j4 + 3]) + m;
        o4[j4] = o;
    }
}

extern "C" void kernel_launch(void* const* d_in, const int* in_sizes, int n_in,
                              void* d_out, int out_size, void* d_ws, size_t ws_size,
                              hipStream_t stream) {
    const float* x   = (const float*)d_in[0];   // [128,8,1024,32] fp32
    const float* acc = (const float*)d_in[1];   // [128,8,32,32]  fp32
    float* out = (float*)d_out;                 // [128,8,1024,32] fp32

    dim3 grid(4096);   // 1024 (s,d) pairs * 4 row-tiles
    dim3 block(THREADS);
    hipLaunchKernelGGL(sws_kernel, grid, block, 0, stream, x, acc, out);
}

// Round 2
// 235.609 us; speedup vs baseline: 1.0428x; 1.0428x over previous
//
#include <hip/hip_runtime.h>
#include <stdint.h>

// ScopeWiseSum via bf16 MFMA.
// out[s,d,b,j] = log( sum_k exp(x[b,k]-m_b) * w[k,j] ) + m_b,  w = acc / colsum(acc).
// (max_b of the reference logmatmul cancels against log_softmax analytically)
//
// R1 post-mortem: scalar-FMA version was LDS-issue-bound (256 ds_read_b128/thread
// for the broadcast w reads ~= 82 us/CU serialized). MFMA cuts per-lane LDS ops
// ~300 -> ~40 and moves the dot to the matrix pipe.

#define THREADS 256
#define ROWS    256       // rows per block
#define EPITCH  40        // halves per e-row (32 + 8 pad; 80 B stride, 16B-aligned, banks rotate)
#define WPITCH  40

typedef __attribute__((ext_vector_type(8))) short short8;   // 8 bf16 = 4 VGPRs (MFMA A/B frag)
typedef __attribute__((ext_vector_type(4))) float f32x4;    // MFMA C/D frag

__device__ __forceinline__ uint32_t pack2_bf16(float lo, float hi) {
    uint32_t ul = __builtin_bit_cast(uint32_t, lo);
    uint32_t uh = __builtin_bit_cast(uint32_t, hi);
    ul = (ul + 0x7fffu + ((ul >> 16) & 1u)) >> 16;   // RNE truncate to bf16
    uh = (uh + 0x7fffu + ((uh >> 16) & 1u)) >> 16;
    return ul | (uh << 16);
}

__global__ __launch_bounds__(THREADS, 4) void sws_kernel(
    const float* __restrict__ x,
    const float* __restrict__ acc,
    float* __restrict__ out)
{
    __shared__ float w_f32[32 * 32];                         // raw acc tile (fp32)
    __shared__ float inv_lds[32];                            // 1/colsum
    __shared__ float m_lds[ROWS];                            // per-row max
    __shared__ __align__(16) unsigned short e_lds[ROWS * EPITCH];  // bf16 exp(x-m)
    __shared__ __align__(16) unsigned short wt_lds[32 * WPITCH];   // bf16 w^T [j][k]

    const int t    = threadIdx.x;
    const int blk  = blockIdx.x;
    const int sd   = blk >> 2;            // 4 row-tiles of 256 per (s,d)
    const int lane = t & 63;
    const int wv   = t >> 6;
    const int l15  = lane & 15;
    const int quad = lane >> 4;

    // ---- issue coalesced x loads first (lane i -> consecutive float4) ----
    const float4* x4 = (const float4*)(x + (size_t)blk * ROWS * 32);
    float4 xv[8];
#pragma unroll
    for (int i = 0; i < 8; ++i) xv[i] = x4[t + i * THREADS];

    // ---- weights: load acc tile, column-normalize, bf16, store transposed ----
    const float* a_base = acc + (size_t)sd * (32 * 32);
    {
        float av[4];
#pragma unroll
        for (int i = 0; i < 4; ++i) av[i] = a_base[t + i * THREADS];
#pragma unroll
        for (int i = 0; i < 4; ++i) w_f32[t + i * THREADS] = av[i];
    }
    __syncthreads();
    if (t < 32) {
        float s = 0.f;
#pragma unroll
        for (int k = 0; k < 32; ++k) s += w_f32[k * 32 + t];  // bank t: conflict-free
        inv_lds[t] = 1.0f / s;
    }
    __syncthreads();
#pragma unroll
    for (int i = 0; i < 4; ++i) {
        int idx = t + i * THREADS;
        int k = idx >> 5, j = idx & 31;
        float v = w_f32[idx] * inv_lds[j];
        uint32_t u = __builtin_bit_cast(uint32_t, v);
        u = (u + 0x7fffu + ((u >> 16) & 1u)) >> 16;
        wt_lds[j * WPITCH + k] = (unsigned short)u;          // w^T: k contiguous per j
    }

    // ---- e phase: row max via 8-lane shfl groups, exp, bf16, stage to LDS ----
    // f = t + 256*i; row = f>>3 (8 float4 per row); lanes [8a,8a+8) share a row.
#pragma unroll
    for (int i = 0; i < 8; ++i) {
        float4 v = xv[i];
        float m = fmaxf(fmaxf(v.x, v.y), fmaxf(v.z, v.w));
        m = fmaxf(m, __shfl_xor(m, 1, 64));
        m = fmaxf(m, __shfl_xor(m, 2, 64));
        m = fmaxf(m, __shfl_xor(m, 4, 64));
        int f = t + i * THREADS;
        int row = f >> 3, c4 = f & 7;
        uint32_t p0 = pack2_bf16(__expf(v.x - m), __expf(v.y - m));
        uint32_t p1 = pack2_bf16(__expf(v.z - m), __expf(v.w - m));
        *(uint2*)&e_lds[row * EPITCH + c4 * 4] = make_uint2(p0, p1);
        if (c4 == 0) m_lds[row] = m;
    }
    __syncthreads();

    // ---- MFMA: each wave owns 4 row-tiles x 2 j-tiles = 8 mfma_f32_16x16x32_bf16 ----
    // A[m=lane&15][k=quad*8+i] ; B^T stored as [n][k] (m92 convention) ; C: col=lane&15,
    // row=(lane>>4)*4+reg (m89-verified).
    short8 bfrag[2];
#pragma unroll
    for (int jt = 0; jt < 2; ++jt)
        bfrag[jt] = *(const short8*)&wt_lds[(jt * 16 + l15) * WPITCH + quad * 8];

    f32x4 cacc[4][2];
#pragma unroll
    for (int rt4 = 0; rt4 < 4; ++rt4) {
        int rt = wv * 4 + rt4;
        short8 afrag = *(const short8*)&e_lds[(rt * 16 + l15) * EPITCH + quad * 8];
#pragma unroll
        for (int jt = 0; jt < 2; ++jt)
            cacc[rt4][jt] = __builtin_amdgcn_mfma_f32_16x16x32_bf16(
                afrag, bfrag[jt], (f32x4){0.f, 0.f, 0.f, 0.f}, 0, 0, 0);
    }

    // ---- epilogue: log + row max, scalar stores (16-lane groups write 64B segments) ----
    float* obase = out + (size_t)blk * ROWS * 32;
#pragma unroll
    for (int rt4 = 0; rt4 < 4; ++rt4) {
        int rt = wv * 4 + rt4;
        int r0 = rt * 16 + quad * 4;
        float4 mv = *(const float4*)&m_lds[r0];   // 16B-aligned, broadcast per 16-lane group
        float mr[4] = {mv.x, mv.y, mv.z, mv.w};
#pragma unroll
        for (int jt = 0; jt < 2; ++jt) {
            int col = jt * 16 + l15;
#pragma unroll
            for (int r = 0; r < 4; ++r) {
                float val = __logf(cacc[rt4][jt][r]) + mr[r];
                obase[(size_t)(r0 + r) * 32 + col] = val;
            }
        }
    }
}

extern "C" void kernel_launch(void* const* d_in, const int* in_sizes, int n_in,
                              void* d_out, int out_size, void* d_ws, size_t ws_size,
                              hipStream_t stream) {
    const float* x   = (const float*)d_in[0];   // [128,8,1024,32] fp32
    const float* acc = (const float*)d_in[1];   // [128,8,32,32]  fp32
    float* out = (float*)d_out;                 // [128,8,1024,32] fp32

    dim3 grid(4096);   // 1024 (s,d) pairs * 4 row-tiles of 256 rows
    dim3 block(THREADS);
    hipLaunchKernelGGL(sws_kernel, grid, block, 0, stream, x, acc, out);
}

// Round 3
// 231.038 us; speedup vs baseline: 1.0635x; 1.0198x over previous
//
#include <hip/hip_runtime.h>
#include <stdint.h>

// ScopeWiseSum via bf16 MFMA, register-resident A-fragments (no e/m LDS staging).
// out[s,d,b,j] = log( sum_k exp(x[b,k]-m_b) * w[k,j] ) + m_b,  w = acc / colsum(acc).
//
// R2 post-mortem: 84 us, all pipes <40% -> latency-bound at 3 blocks/CU (28.6 KB LDS).
// R3: lanes load their MFMA A-frag directly from global (row=rt*16+l15, k=quad*8..+7),
// row-max via shfl_xor(16/32), exp/pack in regs. LDS = 6.3 KB weight phase only;
// ROWS=128, launch_bounds(256,8) -> 8 blocks/CU; x->MFMA path crosses no barrier.

#define THREADS 256
#define ROWS    128      // rows per block -> 8192 blocks

typedef __attribute__((ext_vector_type(8))) short short8;   // MFMA A/B frag (8 bf16)
typedef __attribute__((ext_vector_type(4))) float f32x4;    // MFMA C/D frag
typedef __attribute__((ext_vector_type(4))) int   i32x4;

__device__ __forceinline__ uint32_t pack2_bf16(float lo, float hi) {
    uint32_t ul = __builtin_bit_cast(uint32_t, lo);
    uint32_t uh = __builtin_bit_cast(uint32_t, hi);
    ul = (ul + 0x7fffu + ((ul >> 16) & 1u)) >> 16;   // RNE to bf16
    uh = (uh + 0x7fffu + ((uh >> 16) & 1u)) >> 16;
    return ul | (uh << 16);
}

__device__ __forceinline__ unsigned short bf16_1(float v) {
    uint32_t u = __builtin_bit_cast(uint32_t, v);
    return (unsigned short)((u + 0x7fffu + ((u >> 16) & 1u)) >> 16);
}

__global__ __launch_bounds__(THREADS, 8) void sws_kernel(
    const float* __restrict__ x,
    const float* __restrict__ acc,
    float* __restrict__ out)
{
    __shared__ float w_f32[32 * 32];                        // raw acc tile
    __shared__ float inv_lds[32];                           // 1/colsum
    __shared__ __align__(16) unsigned short wt_lds[32 * 32]; // bf16 w^T [j][k], pitch 32

    const int t    = threadIdx.x;
    const int blk  = blockIdx.x;
    const int sd   = blk >> 3;            // 8 row-tiles of 128 per (s,d)
    const int lane = t & 63;
    const int wv   = t >> 6;
    const int l15  = lane & 15;
    const int quad = lane >> 4;

    // ---- x loads: lane's own A-frag bytes. rt = wv*2+i, row = rt*16+l15,
    //      k = quad*8..+7 -> two consecutive float4 at (row*8 + quad*2) ----
    const float4* x4 = (const float4*)(x + (size_t)blk * ROWS * 32);
    float4 xv[4];
#pragma unroll
    for (int i = 0; i < 2; ++i) {
        int f4 = ((wv * 2 + i) * 16 + l15) * 8 + quad * 2;
        xv[2 * i]     = x4[f4];
        xv[2 * i + 1] = x4[f4 + 1];
    }

    // ---- weight phase (only LDS user): load acc, colsum, normalize, bf16 w^T ----
    const float4 a4 = ((const float4*)(acc + (size_t)sd * 1024))[t];  // k=t>>3, j=(t&7)*4..+3
    *((float4*)&w_f32[t * 4]) = a4;
    __syncthreads();
    if (t < 32) {
        float s = 0.f;
#pragma unroll
        for (int k = 0; k < 32; ++k) s += w_f32[k * 32 + t];  // bank t: conflict-free
        inv_lds[t] = 1.0f / s;
    }
    __syncthreads();
    {
        const int k = t >> 3, j0 = (t & 7) * 4;
        const float4 inv4 = *((const float4*)&inv_lds[j0]);
        wt_lds[(j0 + 0) * 32 + k] = bf16_1(a4.x * inv4.x);
        wt_lds[(j0 + 1) * 32 + k] = bf16_1(a4.y * inv4.y);
        wt_lds[(j0 + 2) * 32 + k] = bf16_1(a4.z * inv4.z);
        wt_lds[(j0 + 3) * 32 + k] = bf16_1(a4.w * inv4.w);
    }

    // ---- e phase: in-register row max (across quads), exp, pack bf16 A-frags ----
    float  mrow[2];
    short8 afrag[2];
#pragma unroll
    for (int i = 0; i < 2; ++i) {
        float4 a = xv[2 * i], b = xv[2 * i + 1];
        float m = fmaxf(fmaxf(fmaxf(a.x, a.y), fmaxf(a.z, a.w)),
                        fmaxf(fmaxf(b.x, b.y), fmaxf(b.z, b.w)));
        m = fmaxf(m, __shfl_xor(m, 16, 64));   // combine the 4 quads holding this row
        m = fmaxf(m, __shfl_xor(m, 32, 64));
        mrow[i] = m;
        i32x4 pk;
        pk[0] = (int)pack2_bf16(__expf(a.x - m), __expf(a.y - m));
        pk[1] = (int)pack2_bf16(__expf(a.z - m), __expf(a.w - m));
        pk[2] = (int)pack2_bf16(__expf(b.x - m), __expf(b.y - m));
        pk[3] = (int)pack2_bf16(__expf(b.z - m), __expf(b.w - m));
        afrag[i] = __builtin_bit_cast(short8, pk);
    }
    __syncthreads();   // wt_lds ready

    // ---- B-frags + MFMA: 2 row-tiles x 2 j-tiles per wave ----
    short8 bfrag[2];
#pragma unroll
    for (int jt = 0; jt < 2; ++jt)
        bfrag[jt] = *(const short8*)&wt_lds[(jt * 16 + l15) * 32 + quad * 8];

    f32x4 cacc[2][2];
#pragma unroll
    for (int i = 0; i < 2; ++i)
#pragma unroll
        for (int jt = 0; jt < 2; ++jt)
            cacc[i][jt] = __builtin_amdgcn_mfma_f32_16x16x32_bf16(
                afrag[i], bfrag[jt], (f32x4){0.f, 0.f, 0.f, 0.f}, 0, 0, 0);

    // ---- epilogue: C layout col=l15, row=quad*4+r. m via width-16 shfl
    //      (lane at position quad*4+r holds that row's max) ----
    float* ob = out + (size_t)blk * ROWS * 32;
#pragma unroll
    for (int i = 0; i < 2; ++i) {
        int rbase = ((wv * 2 + i) * 16) + quad * 4;
#pragma unroll
        for (int r = 0; r < 4; ++r) {
            float mr = __shfl(mrow[i], quad * 4 + r, 16);
            float* orow = ob + (size_t)(rbase + r) * 32;
            orow[l15]      = __logf(cacc[i][0][r]) + mr;
            orow[l15 + 16] = __logf(cacc[i][1][r]) + mr;
        }
    }
}

extern "C" void kernel_launch(void* const* d_in, const int* in_sizes, int n_in,
                              void* d_out, int out_size, void* d_ws, size_t ws_size,
                              hipStream_t stream) {
    const float* x   = (const float*)d_in[0];   // [128,8,1024,32] fp32
    const float* acc = (const float*)d_in[1];   // [128,8,32,32]  fp32
    float* out = (float*)d_out;                 // [128,8,1024,32] fp32

    dim3 grid(8192);   // 1024 (s,d) pairs * 8 row-tiles of 128 rows
    dim3 block(THREADS);
    hipLaunchKernelGGL(sws_kernel, grid, block, 0, stream, x, acc, out);
}